// Round 6
// baseline (5112.348 us; speedup 1.0000x reference)
//
#include <hip/hip_runtime.h>
#include <hip/hip_bf16.h>

// B=64, S=512, T=64, E=H=512, V=128, G=2048, Kgates=1152
// R6: 2 grid barriers/step. P0 folded into P1 via per-b sibling sync (q2-slice
// per block). All mutable cross-block data b-major + 8B uncached atomics.
// P2: 16 ks x 32 nc (K=72, N=64), LDS 39.4 KB -> 4 blocks/CU.

#define DI __device__ __forceinline__
typedef __hip_bfloat16 bf16;
typedef __hip_bfloat162 bf162;
#define AGENT __HIP_MEMORY_SCOPE_AGENT

DI float aload(const float* p) { return __hip_atomic_load(p, __ATOMIC_RELAXED, AGENT); }
DI void astore(float* p, float v) { __hip_atomic_store(p, v, __ATOMIC_RELAXED, AGENT); }
DI unsigned uload(const unsigned* p) { return __hip_atomic_load(p, __ATOMIC_RELAXED, AGENT); }
DI float2 aload2(const float* p) {
  unsigned long long v = __hip_atomic_load((const unsigned long long*)p, __ATOMIC_RELAXED, AGENT);
  float2 r; *(unsigned long long*)&r = v; return r;
}
DI void astore2(float* p, float x, float y) {
  float2 v = make_float2(x, y);
  __hip_atomic_store((unsigned long long*)p, *(unsigned long long*)&v, __ATOMIC_RELAXED, AGENT);
}
DI float2 bf2f2(unsigned u) { bf162 b = *reinterpret_cast<const bf162*>(&u); return __bfloat1622float2(b); }
DI float sigm(float x) { return 1.f / (1.f + expf(-x)); }

// ---------------------------------------------------------------------------
// Plain fp32 64x64 GEMM (precompute only): C = A(MxK,lda) @ B(KxN,ldb)
// ---------------------------------------------------------------------------
__launch_bounds__(256)
__global__ void gemm64(const float* __restrict__ A, const float* __restrict__ Bm,
                       float* __restrict__ C, int M, int N, int K,
                       int lda, int ldb, int ldc) {
  __shared__ __align__(16) float As[16][68];
  __shared__ __align__(16) float Bs[16][68];
  const int tid = threadIdx.x;
  const int n0 = blockIdx.x * 64, m0 = blockIdx.y * 64;
  const int tx = tid & 15, ty = tid >> 4;
  const int arow = tid >> 2, acol = (tid & 3) * 4;
  float acc[4][4] = {};
  for (int k0 = 0; k0 < K; k0 += 16) {
    float4 a4 = *(const float4*)&A[(size_t)(m0 + arow) * lda + k0 + acol];
    As[acol + 0][arow] = a4.x; As[acol + 1][arow] = a4.y;
    As[acol + 2][arow] = a4.z; As[acol + 3][arow] = a4.w;
    {
      const int brow = tid >> 4, bcol = (tid & 15) * 4;
      float4 b4 = *(const float4*)&Bm[(size_t)(k0 + brow) * ldb + n0 + bcol];
      *(float4*)&Bs[brow][bcol] = b4;
    }
    __syncthreads();
#pragma unroll
    for (int kk = 0; kk < 16; kk++) {
      float4 av = *(const float4*)&As[kk][ty * 4];
      float4 bv = *(const float4*)&Bs[kk][tx * 4];
      float a_[4] = {av.x, av.y, av.z, av.w};
      float b_[4] = {bv.x, bv.y, bv.z, bv.w};
#pragma unroll
      for (int i = 0; i < 4; i++)
#pragma unroll
        for (int j = 0; j < 4; j++) acc[i][j] += a_[i] * b_[j];
    }
    __syncthreads();
  }
#pragma unroll
  for (int i = 0; i < 4; i++)
#pragma unroll
    for (int j = 0; j < 4; j++)
      C[(size_t)(m0 + ty * 4 + i) * ldc + n0 + tx * 4 + j] = acc[i][j];
}

// ---------------------------------------------------------------------------
// Precompute kernels
// ---------------------------------------------------------------------------
__launch_bounds__(256)
__global__ void cast_mem(const float* __restrict__ src, bf16* __restrict__ dst) {
  size_t i = ((size_t)blockIdx.x * 256 + threadIdx.x) * 8;
  float4 a = *(const float4*)&src[i];
  float4 b = *(const float4*)&src[i + 4];
  bf16 o[8] = {__float2bfloat16(a.x), __float2bfloat16(a.y), __float2bfloat16(a.z),
               __float2bfloat16(a.w), __float2bfloat16(b.x), __float2bfloat16(b.y),
               __float2bfloat16(b.z), __float2bfloat16(b.w)};
  *(uint4*)&dst[i] = *(const uint4*)o;
}

__launch_bounds__(256)
__global__ void transpose512(const float* __restrict__ src, float* __restrict__ dst) {
  int idx = blockIdx.x * 256 + threadIdx.x;
  int r = idx >> 9, c = idx & 511;
  dst[(size_t)c * 512 + r] = src[idx];
}

// outv[e] = sum_f bvec[f] * W[f*512 + e]
__launch_bounds__(256)
__global__ void colvec_kernel(const float* __restrict__ bvec, const float* __restrict__ W,
                              float* __restrict__ outv) {
  int e = blockIdx.x * 256 + threadIdx.x;
  float acc = 0.f;
  for (int f = 0; f < 512; f++) acc += bvec[f] * W[(size_t)f * 512 + e];
  outv[e] = acc;
}

// W0aT[e][d] = A[d][e]*SCALE ; bias0s[e] = c0[e]*SCALE
__launch_bounds__(256)
__global__ void makeW0aT(const float* __restrict__ A, const float* __restrict__ c0,
                         float* __restrict__ W0aT, float* __restrict__ bias0s) {
  const float SCALE = 0.04419417382415922f;
  int idx = blockIdx.x * 256 + threadIdx.x;   // < 512*512
  int e = idx >> 9, d = idx & 511;
  W0aT[idx] = A[(size_t)d * 512 + e] * SCALE;
  if (d == 0) bias0s[e] = c0[e] * SCALE;
}

// bvo[a] = sum_x bv[x]*Wo[a][x] + bo[a]
__launch_bounds__(256)
__global__ void bvo_kernel(const float* __restrict__ bv, const float* __restrict__ Wo,
                           const float* __restrict__ bo, float* __restrict__ bvo) {
  int a = blockIdx.x * 256 + threadIdx.x;
  float acc = bo[a];
  const float4* wr = (const float4*)&Wo[(size_t)a * 512];
  const float4* br = (const float4*)bv;
#pragma unroll 4
  for (int x4 = 0; x4 < 128; x4++) {
    float4 w = wr[x4], bb = br[x4];
    acc += w.x * bb.x + w.y * bb.y + w.z * bb.z + w.w * bb.w;
  }
  bvo[a] = acc;
}

// biasg[j] = b_ih[j] + b_hh[j] + sum_f bvo[f]*W_ih[j,f]
__launch_bounds__(256)
__global__ void biasg_kernel(const float* __restrict__ W_ih, const float* __restrict__ b_ih,
                             const float* __restrict__ b_hh, const float* __restrict__ bvo,
                             float* __restrict__ biasg) {
  int j = blockIdx.x * 256 + threadIdx.x;
  float acc = b_ih[j] + b_hh[j];
  const float4* wr = (const float4*)&W_ih[(size_t)j * 640];
  const float4* br = (const float4*)bvo;
#pragma unroll 4
  for (int f4 = 0; f4 < 128; f4++) {
    float4 w = wr[f4], bb = br[f4];
    acc += w.x * bb.x + w.y * bb.y + w.z * bb.z + w.w * bb.w;
  }
  biasg[j] = acc;
}

__launch_bounds__(256)
__global__ void reorderB(const float* __restrict__ bg, float* __restrict__ bg2) {
  int jp = blockIdx.x * 256 + threadIdx.x;
  bg2[jp] = bg[(size_t)(jp & 3) * 512 + (jp >> 2)];
}

// Wg[k][j'=d*4+g] (1152x2048): k<512 -> U2[j][k]; k<1024 -> W_hh[j][k-512];
// else W_ih[j][512+(k-1024)] (lda 640), with j = g*512+d.
__launch_bounds__(256)
__global__ void assembleWg(const float* __restrict__ U2, const float* __restrict__ W_hh,
                           const float* __restrict__ W_ih, float* __restrict__ Wg) {
  int idx = blockIdx.x * 256 + threadIdx.x;   // < 1152*2048
  int k = idx >> 11, jp = idx & 2047;
  int d = jp >> 2, g = jp & 3, j = g * 512 + d;
  float v;
  if (k < 512)       v = U2[(size_t)j * 512 + k];
  else if (k < 1024) v = W_hh[(size_t)j * 512 + (k - 512)];
  else               v = W_ih[(size_t)j * 640 + 512 + (k - 1024)];
  Wg[idx] = v;
}

// ---------------------------------------------------------------------------
// Persistent step loop: 512 blocks x 256 threads, 2 grid barriers/step.
// ---------------------------------------------------------------------------
struct SMemA { float hs[512]; float q2L[512]; float sp[256]; float p[64]; float buf[2080]; };
struct SMemB { float rL[64]; __align__(16) float As[72][68]; __align__(16) float Bs[72][68]; };
union SMemU { SMemA a; SMemB b; };   // 39.4 KB -> 4 blocks/CU (LDS)

// flags/go: one 128B line per block. No shared-line polling.
DI void gbar(unsigned* flags, unsigned* go, int slot) {
  const unsigned tgt = (unsigned)slot + 1u;
  const int tid = threadIdx.x, blk = blockIdx.x;
  __syncthreads();
  if (tid == 0)
    __hip_atomic_store(&flags[blk * 32], tgt, __ATOMIC_RELEASE, AGENT);
  if (blk == 0) {
    while (uload(&flags[tid * 32]) < tgt || uload(&flags[(tid + 256) * 32]) < tgt)
      __builtin_amdgcn_s_sleep(1);
    __syncthreads();
    __hip_atomic_store(&go[tid * 32], tgt, __ATOMIC_RELEASE, AGENT);
    __hip_atomic_store(&go[(tid + 256) * 32], tgt, __ATOMIC_RELEASE, AGENT);
  } else if (tid == 0) {
    while (uload(&go[blk * 32]) < tgt)
      __builtin_amdgcn_s_sleep(1);
  }
  __asm__ __volatile__("" ::: "memory");
  __syncthreads();
}

__launch_bounds__(256, 3)
__global__ void step_loop(const bf16* __restrict__ memb, const float* __restrict__ W0aT,
                          const float* __restrict__ bias0s, const float* __restrict__ Wg,
                          const float* __restrict__ biasg2, const float* __restrict__ tgt,
                          const float* __restrict__ Wcls, const float* __restrict__ bcls,
                          float* __restrict__ q2, float* __restrict__ uacc,
                          float* __restrict__ Lacc, float* __restrict__ hA,
                          float* __restrict__ hB, float* __restrict__ gpart,
                          unsigned* flags, unsigned* go, unsigned* qcnt, unsigned* gcnt,
                          float* __restrict__ out) {
  __shared__ SMemU sm;
  const int blk = blockIdx.x, tid = threadIdx.x;
  const int b = blk >> 3, jj = blk & 7, s0 = jj * 64;   // P1 role
  const int ks = blk >> 5, nc = blk & 31;               // P2 role
  float cval = 0.f;                                     // register c-state (P2 cell)
  int slot = 0;

  for (int t = 0; t <= 64; t++) {
    const float* hR = (t & 1) ? hB : hA;
    float* hW = (t & 1) ? hA : hB;

    // =================== P1: q2-slice + attention (8 blocks/b) =============
    {
      float2 h2 = aload2(&hR[(size_t)b * 512 + 2 * tid]);
      *(float2*)&sm.a.hs[2 * tid] = h2;
    }
    __syncthreads();

    // classifier: out[t-1] (16 v's per block), uses h_t in LDS
    if (t > 0) {
      const int v = jj * 16 + (tid >> 4), part = tid & 15;
      const float4* wr = (const float4*)&Wcls[(size_t)v * 512 + part * 32];
      const float4* hr = (const float4*)&sm.a.hs[part * 32];
      float a = 0.f;
#pragma unroll
      for (int q = 0; q < 8; q++) {
        float4 w = wr[q], x = hr[q];
        a += w.x * x.x + w.y * x.y + w.z * x.z + w.w * x.w;
      }
      a += __shfl_xor(a, 1); a += __shfl_xor(a, 2);
      a += __shfl_xor(a, 4); a += __shfl_xor(a, 8);
      if (part == 0) out[((size_t)b * 64 + (t - 1)) * 128 + v] = a + bcls[v];
    }
    if (t == 64) return;

    // q2-slice: e = jj*64 + (tid>>2), k-quarter dq = tid&3 (W0aT cached)
    {
      const int e_loc = tid >> 2, dq = tid & 3;
      const int e = jj * 64 + e_loc;
      const float4* wrow = (const float4*)&W0aT[(size_t)e * 512 + dq * 128];
      const float4* hrow = (const float4*)&sm.a.hs[dq * 128];
      float qa = 0.f;
#pragma unroll
      for (int j = 0; j < 32; j++) {
        float4 w = wrow[j], hh = hrow[j];
        qa += w.x * hh.x + w.y * hh.y + w.z * hh.z + w.w * hh.w;
      }
      qa += __shfl_xor(qa, 1); qa += __shfl_xor(qa, 2);
      if (dq == 0) astore(&q2[(size_t)b * 512 + e], qa + bias0s[e]);
    }
    // zero uacc slice; jj==0 zeros Lacc[b]
    if (tid < 32) astore2(&uacc[(size_t)b * 512 + jj * 64 + 2 * tid], 0.f, 0.f);
    if (jj == 0 && tid == 0) astore(&Lacc[b * 32], 0.f);
    __syncthreads();   // drain all stores (waitcnt) before publishing
    if (tid == 0) {
      __hip_atomic_fetch_add(&qcnt[b * 32], 1u, __ATOMIC_RELEASE, AGENT);
      while (uload(&qcnt[b * 32]) < 8u * (t + 1))
        __builtin_amdgcn_s_sleep(1);
    }
    __asm__ __volatile__("" ::: "memory");
    __syncthreads();
    // full q2[b] -> LDS
    {
      float2 v = aload2(&q2[(size_t)b * 512 + 2 * tid]);
      *(float2*)&sm.a.q2L[2 * tid] = v;
    }
    __syncthreads();
    // scores: s = tid>>2 (0..63), e-quarter = (tid&3)*128 (memb cached)
    {
      const int s = tid >> 2, eq = tid & 3;
      const uint4* mp = (const uint4*)&memb[((size_t)b << 18) + (size_t)(s0 + s) * 512 + eq * 128];
      const float4* qp = (const float4*)&sm.a.q2L[eq * 128];
      float acc = 0.f;
#pragma unroll 8
      for (int j = 0; j < 16; j++) {
        uint4 m = mp[j];
        float4 qa = qp[2 * j], qb = qp[2 * j + 1];
        float2 p0 = bf2f2(m.x), p1 = bf2f2(m.y), p2 = bf2f2(m.z), p3 = bf2f2(m.w);
        acc += p0.x * qa.x + p0.y * qa.y + p1.x * qa.z + p1.y * qa.w
             + p2.x * qb.x + p2.y * qb.y + p3.x * qb.z + p3.y * qb.w;
      }
      sm.a.sp[tid] = acc;
    }
    __syncthreads();
    if (tid < 64) {
      float sc = sm.a.sp[4 * tid] + sm.a.sp[4 * tid + 1] + sm.a.sp[4 * tid + 2] + sm.a.sp[4 * tid + 3];
      float es = __expf(sc);            // no max-sub: |score| << 10 by construction
      sm.a.p[tid] = es;
      float ls = es;
#pragma unroll
      for (int off = 32; off; off >>= 1) ls += __shfl_xor(ls, off);
      if (tid == 0) atomicAdd(&Lacc[b * 32], ls);
    }
    __syncthreads();
    // u-partials: wave w covers 16 s's, lane l covers e = 8l..8l+7
    {
      const int w = tid >> 6, l = tid & 63;
      float c8[8] = {};
      const uint4* vp = (const uint4*)&memb[((size_t)b << 18) + (size_t)(s0 + w * 16) * 512 + 8 * l];
#pragma unroll 8
      for (int i = 0; i < 16; i++) {
        float ps = sm.a.p[w * 16 + i];
        uint4 m = vp[(size_t)i * 64];
        float2 p0 = bf2f2(m.x), p1 = bf2f2(m.y), p2 = bf2f2(m.z), p3 = bf2f2(m.w);
        c8[0] += ps * p0.x; c8[1] += ps * p0.y; c8[2] += ps * p1.x; c8[3] += ps * p1.y;
        c8[4] += ps * p2.x; c8[5] += ps * p2.y; c8[6] += ps * p3.x; c8[7] += ps * p3.y;
      }
      *(float4*)&sm.a.buf[w * 520 + 8 * l]     = make_float4(c8[0], c8[1], c8[2], c8[3]);
      *(float4*)&sm.a.buf[w * 520 + 8 * l + 4] = make_float4(c8[4], c8[5], c8[6], c8[7]);
    }
    __syncthreads();
    {
      const int e = 2 * tid;
      float ux = sm.a.buf[e] + sm.a.buf[520 + e] + sm.a.buf[1040 + e] + sm.a.buf[1560 + e];
      float uy = sm.a.buf[e + 1] + sm.a.buf[520 + e + 1] + sm.a.buf[1040 + e + 1] + sm.a.buf[1560 + e + 1];
      atomicAdd(&uacc[(size_t)b * 512 + e], ux);        // coalesced (b-major)
      atomicAdd(&uacc[(size_t)b * 512 + e + 1], uy);
    }
    gbar(flags, go, slot++);

    // ========== P2: gates GEMM (16 ks x 32 nc, K=72, N=64) + cell ==========
    {
      const int k0 = ks * 72;
      if (tid < 64) sm.b.rL[tid] = 1.0f / aload(&Lacc[tid * 32]);
      __syncthreads();
      // stage As[k][b] (72 x 64): per-b contiguous k-pairs (uncached u64)
      for (int q = tid; q < 2304; q += 256) {
        const int bb = q / 36, kp = q - bb * 36;
        const int k = k0 + kp * 2;
        float2 xv;
        if (k < 512) {
          xv = aload2(&uacc[(size_t)bb * 512 + k]);
          const float r = sm.b.rL[bb];
          xv.x *= r; xv.y *= r;
        } else if (k < 1024) {
          xv = aload2(&hR[(size_t)bb * 512 + (k - 512)]);
        } else {
          xv = *(const float2*)&tgt[((size_t)bb * 64 + t) * 128 + (k - 1024)];
        }
        sm.b.As[kp * 2][bb] = xv.x;
        sm.b.As[kp * 2 + 1][bb] = xv.y;
      }
      // stage Bs[k][j] (72 x 64): Wg cached float4
      for (int q = tid; q < 1152; q += 256) {
        const int row = q >> 4, c4 = (q & 15) * 4;
        *(float4*)&sm.b.Bs[row][c4] = *(const float4*)&Wg[(size_t)(k0 + row) * 2048 + nc * 64 + c4];
      }
      __syncthreads();
      const int tx = tid & 15, ty = tid >> 4;
      float acc[4][4] = {};
#pragma unroll 4
      for (int kk = 0; kk < 72; kk++) {
        float4 av = *(const float4*)&sm.b.As[kk][ty * 4];
        float4 bv = *(const float4*)&sm.b.Bs[kk][tx * 4];
        float a_[4] = {av.x, av.y, av.z, av.w};
        float b_[4] = {bv.x, bv.y, bv.z, bv.w};
#pragma unroll
        for (int i = 0; i < 4; i++)
#pragma unroll
          for (int j = 0; j < 4; j++) acc[i][j] += a_[i] * b_[j];
      }
#pragma unroll
      for (int i = 0; i < 4; i++) {
        const size_t gp = ((size_t)ks * 64 + ty * 4 + i) * 2048 + nc * 64 + tx * 4;
        astore2(&gpart[gp], acc[i][0], acc[i][1]);
        astore2(&gpart[gp + 2], acc[i][2], acc[i][3]);
      }
    }
    __syncthreads();
    if (tid == 0) {
      __hip_atomic_fetch_add(&gcnt[nc * 32], 1u, __ATOMIC_RELEASE, AGENT);
      while (uload(&gcnt[nc * 32]) < 16u * (t + 1))
        __builtin_amdgcn_s_sleep(1);
    }
    __asm__ __volatile__("" ::: "memory");
    __syncthreads();
    // cell: this block handles b in [ks*4, ks*4+4), d in [nc*16, nc*16+16)
    if (tid < 64) {
      const int bb = ks * 4 + (tid >> 4);
      const int dl = tid & 15;
      const int jb = nc * 64 + dl * 4;      // j' base = d*4
      float g0 = biasg2[jb], g1 = biasg2[jb + 1], g2 = biasg2[jb + 2], g3 = biasg2[jb + 3];
#pragma unroll
      for (int k2 = 0; k2 < 16; k2++) {
        const float* gp = &gpart[((size_t)k2 * 64 + bb) * 2048 + jb];
        float2 ga = aload2(gp), gb = aload2(gp + 2);
        g0 += ga.x; g1 += ga.y; g2 += gb.x; g3 += gb.y;
      }
      float cn = sigm(g1) * cval + sigm(g0) * tanhf(g2);
      cval = cn;
      float hn = sigm(g3) * tanhf(cn);
      astore(&hW[(size_t)bb * 512 + nc * 16 + dl], hn);
    }
    gbar(flags, go, slot++);
  }
}

// ---------------------------------------------------------------------------
extern "C" void kernel_launch(void* const* d_in, const int* in_sizes, int n_in,
                              void* d_out, int out_size, void* d_ws, size_t ws_size,
                              hipStream_t stream) {
  const float* memory = (const float*)d_in[0];
  const float* tgt    = (const float*)d_in[1];
  const float* Wq     = (const float*)d_in[2];
  const float* bq     = (const float*)d_in[3];
  const float* Wk     = (const float*)d_in[4];
  const float* Wv     = (const float*)d_in[6];
  const float* bv     = (const float*)d_in[7];
  const float* Wo     = (const float*)d_in[8];
  const float* bo     = (const float*)d_in[9];
  const float* W_ih   = (const float*)d_in[10];
  const float* b_ih   = (const float*)d_in[11];
  const float* W_hh   = (const float*)d_in[12];
  const float* b_hh   = (const float*)d_in[13];
  const float* Wcls   = (const float*)d_in[14];
  const float* bcls   = (const float*)d_in[15];
  float* out = (float*)d_out;

  float* ws = (float*)d_ws;
  size_t off = 0;
  auto alloc = [&](size_t n) { size_t r = off; off += (n + 31) & ~(size_t)31; return r; };
  const size_t memb_off   = alloc(8388608);    // bf16 x 16.7M [b][s][e]
  const size_t Wg_off     = alloc(2359296);    // fp32 [k][j'] 1152x2048
  const size_t W0aT_off   = alloc(262144);     // fp32 [e][d]
  const size_t bias0s_off = alloc(512);
  const size_t biasg_off  = alloc(2048);
  const size_t biasg2_off = alloc(2048);
  const size_t bvo_off    = alloc(512);
  const size_t c0_off     = alloc(512);
  const size_t q2_off     = alloc(32768);      // [b][e]
  const size_t uacc_off   = alloc(32768);      // [b][e]
  const size_t Lacc_off   = alloc(2048);       // 64 x 32 (128B stride)
  const size_t hA_off     = alloc(32768);      // zeroed
  const size_t sync_off   = alloc(35840);      // flags+go+qcnt+gcnt (zeroed, uints)
  const size_t hB_off     = alloc(32768);
  const size_t gpart_off  = alloc(2097152);    // 16x64x2048; aliases U2 in precompute
  const size_t WqT_off    = alloc(262144);
  const size_t A_off      = alloc(262144);
  const size_t U1_off     = alloc(262144);

  bf16* memb = (bf16*)(ws + memb_off);
  unsigned* sync  = (unsigned*)(ws + sync_off);
  unsigned* flags = sync;            // 512*32
  unsigned* gosig = sync + 16384;    // 512*32
  unsigned* qcnt  = sync + 32768;    // 64*32
  unsigned* gcnt  = sync + 34816;    // 32*32
  float* U2 = ws + gpart_off;        // precompute alias

  // zero hA + sync (contiguous)
  hipMemsetAsync(ws + hA_off, 0, (32768 + 35840) * sizeof(float), stream);

  // ---- precompute ----
  cast_mem<<<8192, 256, 0, stream>>>(memory, memb);
  transpose512<<<1024, 256, 0, stream>>>(Wq, ws + WqT_off);
  gemm64<<<dim3(8, 8), 256, 0, stream>>>(ws + WqT_off, Wk, ws + A_off,
                                         512, 512, 512, 512, 512, 512);   // A = Wq^T Wk
  colvec_kernel<<<2, 256, 0, stream>>>(bq, Wk, ws + c0_off);              // c0 = bq@Wk
  makeW0aT<<<1024, 256, 0, stream>>>(ws + A_off, ws + c0_off, ws + W0aT_off, ws + bias0s_off);
  gemm64<<<dim3(8, 8), 256, 0, stream>>>(Wo, Wv, ws + U1_off,
                                         512, 512, 512, 512, 512, 512);   // U1 = Wo@Wv
  gemm64<<<dim3(8, 32), 256, 0, stream>>>(W_ih, ws + U1_off, U2,
                                          2048, 512, 512, 640, 512, 512); // U2 = W1@U1
  assembleWg<<<9216, 256, 0, stream>>>(U2, W_hh, W_ih, ws + Wg_off);
  bvo_kernel<<<2, 256, 0, stream>>>(bv, Wo, bo, ws + bvo_off);
  biasg_kernel<<<8, 256, 0, stream>>>(W_ih, b_ih, b_hh, ws + bvo_off, ws + biasg_off);
  reorderB<<<8, 256, 0, stream>>>(ws + biasg_off, ws + biasg2_off);

  // ---- all 64 recurrent steps, one persistent kernel ----
  step_loop<<<512, 256, 0, stream>>>(memb, ws + W0aT_off, ws + bias0s_off,
                                     ws + Wg_off, ws + biasg2_off, tgt, Wcls, bcls,
                                     ws + q2_off, ws + uacc_off, ws + Lacc_off,
                                     ws + hA_off, ws + hB_off, ws + gpart_off,
                                     flags, gosig, qcnt, gcnt, out);
}